// Round 8
// baseline (285.152 us; speedup 1.0000x reference)
//
#include <hip/hip_runtime.h>
#include <hip/hip_bf16.h>

#define NEG_INF -9.0e15f

using u16 = unsigned short;
typedef float f32x4 __attribute__((ext_vector_type(4)));
typedef short s16x8 __attribute__((ext_vector_type(8)));

__device__ __forceinline__ float b2f(__hip_bfloat16 v) { return __bfloat162float(v); }
__device__ __forceinline__ float ldv(const float* p, int i) { return p[i]; }
__device__ __forceinline__ float ldv(const __hip_bfloat16* p, int i) { return __bfloat162float(p[i]); }
__device__ __forceinline__ float bu2f(u16 u) { return __uint_as_float(((unsigned)u) << 16); }
__device__ __forceinline__ u16 f2bu(float v) {
    __hip_bfloat16 h = __float2bfloat16(v);
    return *(u16*)&h;
}

__device__ __forceinline__ void ld8f(const float* p, float* f) {
    const float4* q = (const float4*)p;
    float4 a = q[0], b = q[1];
    f[0]=a.x; f[1]=a.y; f[2]=a.z; f[3]=a.w; f[4]=b.x; f[5]=b.y; f[6]=b.z; f[7]=b.w;
}
__device__ __forceinline__ void ld8f(const __hip_bfloat16* p, float* f) {
    uint4 r = *(const uint4*)p;
    f[0]=__uint_as_float(r.x<<16); f[1]=__uint_as_float(r.x&0xffff0000u);
    f[2]=__uint_as_float(r.y<<16); f[3]=__uint_as_float(r.y&0xffff0000u);
    f[4]=__uint_as_float(r.z<<16); f[5]=__uint_as_float(r.z&0xffff0000u);
    f[6]=__uint_as_float(r.w<<16); f[7]=__uint_as_float(r.w&0xffff0000u);
}

__device__ __forceinline__ void async16(const void* g, void* l) {
    __builtin_amdgcn_global_load_lds(
        (__attribute__((address_space(1))) void*)(g),
        (__attribute__((address_space(3))) void*)(l), 16, 0, 0);
}

__device__ __forceinline__ f32x4 mfma16(s16x8 a, s16x8 b, f32x4 c) {
    return __builtin_amdgcn_mfma_f32_16x16x32_bf16(a, b, c, 0, 0, 0);
}

// wave-level dtype sniff (uniform per wave): bf16 weights -> sane exponents.
__device__ __forceinline__ int sniff(const void* wnode) {
    const u16* w = (const u16*)wnode;
    int lane = threadIdx.x & 63;
    u16 u = w[2 * lane];
    int e = (u >> 7) & 0xFF;
    unsigned long long m = __ballot(e >= 100 && e <= 140);
    return __popcll(m) >= 48;
}

// ------------- k_wt: Wt[l][n][k] = W[l][k][n]; Wnt[n][k] (K pad 96, zeros) --
__global__ __launch_bounds__(256) void k_wt(
    const void* __restrict__ gat_W, const void* __restrict__ W_node,
    u16* __restrict__ Wt, u16* __restrict__ Wnt) {
    if (!sniff(W_node)) return;   // f32 path never uses Wt/Wnt
    int b = blockIdx.x, t = threadIdx.x;
    if (b < 24) {
        int l = b >> 3, nb = (b & 7) * 32;
        const u16* Ws = (const u16*)gat_W + (size_t)l * 65536;
        u16* Wd = Wt + (size_t)l * 65536;
        int n = nb + (t & 31), kc = t >> 5;
        u16 tmp[32];
        #pragma unroll 8
        for (int kk = 0; kk < 32; ++kk) tmp[kk] = Ws[(kc * 32 + kk) * 256 + n];
        #pragma unroll
        for (int kk = 0; kk < 32; ++kk) Wd[n * 256 + kc * 32 + kk] = tmp[kk];
    } else {
        int nb = (b - 24) * 128;
        const u16* Ws = (const u16*)W_node;
        int n = nb + (t >> 1), hf = t & 1;
        for (int kk = 0; kk < 48; ++kk) {
            int k = hf * 48 + kk;
            Wnt[n * 96 + k] = (k < 78) ? Ws[k * 256 + n] : (u16)0;
        }
    }
}

// ------------- k_gat (MFMA): h = x@W[l]; s1/s2 partials per N-half ----------
// grid 512: rb=bx>>1 (16-row band), nh=bx&1 (128-col half). 4 waves.
// Wave w: N-cols n0+w*32..+31 (2 tiles). A = x split hi/lo bf16.
__global__ __launch_bounds__(256) void k_gat(
    const float* __restrict__ x, const u16* __restrict__ Wt,
    const void* __restrict__ gat_W_raw, const void* __restrict__ gat_a,
    int layer, const void* __restrict__ nf, const u16* __restrict__ Wnt,
    const void* __restrict__ Wn_raw, const void* __restrict__ bn, int first,
    float* __restrict__ h, float* __restrict__ sp1, float* __restrict__ sp2) {
    __shared__ __align__(16) char smem[36864];
    u16* xs_hi = (u16*)smem;                 // [16][264]
    u16* xs_lo = (u16*)(smem + 8448);        // [16][264]
    char* wbB  = smem + 16896;               // 16 KB: B-staging (dbuf 2x8KB / phaseA 16KB)
    u16* nfs   = (u16*)(smem + 33280);       // [16][96]
    float* sred = (float*)(smem + 36352);    // 128 floats

    const int t = threadIdx.x;
    const int w = t >> 6, lane = t & 63, quad = lane >> 4, l16 = lane & 15;
    const int rb = blockIdx.x >> 1, nh = blockIdx.x & 1;
    const int row0 = rb * 16, n0 = nh * 128;
    const int isbf = sniff(Wn_raw);

    if (isbf) {
        // ---------- build xs_hi/xs_lo (A-side, full K=256) ----------
        if (first) {
            const u16* nfu = (const u16*)nf;
            for (int i = t; i < 16 * 96; i += 256) {
                int r = i / 96, k = i - r * 96;
                nfs[i] = (k < 78) ? nfu[(row0 + r) * 78 + k] : (u16)0;
            }
            __syncthreads();
            // phase A: x-tile = nf @ Wn + b ; wave covers cols w*64..+63
            f32x4 pa[4];
            const u16* bnu = (const u16*)bn;
            #pragma unroll
            for (int tt = 0; tt < 4; ++tt) {
                float bv = bu2f(bnu[w * 64 + tt * 16 + l16]);
                pa[tt] = (f32x4){bv, bv, bv, bv};
            }
            for (int c = 0; c < 3; ++c) {
                #pragma unroll
                for (int j = 0; j < 4; ++j) {
                    int dest = (w * 4 + j) * 4096 + lane * 16;
                    int nl = (w * 4 + j) * 64 + (lane >> 2);
                    const char* src = (const char*)(Wnt + nl * 96 + c * 32 + (lane & 3) * 8);
                    async16(src, wbB + dest);
                }
                __syncthreads();
                s16x8 a = *(const s16x8*)(nfs + l16 * 96 + c * 32 + quad * 8);
                #pragma unroll
                for (int tt = 0; tt < 4; ++tt) {
                    s16x8 bfr = *(const s16x8*)((const u16*)wbB +
                                 (w * 64 + tt * 16 + l16) * 32 + quad * 8);
                    pa[tt] = mfma16(a, bfr, pa[tt]);
                }
                __syncthreads();
            }
            // write x-tile to xs hi/lo: row=quad*4+r, col=w*64+tt*16+l16
            #pragma unroll
            for (int tt = 0; tt < 4; ++tt) {
                #pragma unroll
                for (int r = 0; r < 4; ++r) {
                    float v = pa[tt][r];
                    u16 hi = f2bu(v);
                    u16 lo = f2bu(v - bu2f(hi));
                    int idx = (quad * 4 + r) * 264 + w * 64 + tt * 16 + l16;
                    xs_hi[idx] = hi;
                    xs_lo[idx] = lo;
                }
            }
        } else {
            // load x rows from global, split into hi/lo bf16
            int row = t >> 4, kb = (t & 15) * 16;
            const float4* xp = (const float4*)(x + (size_t)(row0 + row) * 256 + kb);
            float v[16];
            #pragma unroll
            for (int q = 0; q < 4; ++q) {
                float4 f = xp[q];
                v[4*q] = f.x; v[4*q+1] = f.y; v[4*q+2] = f.z; v[4*q+3] = f.w;
            }
            unsigned hp[8], lp[8];
            #pragma unroll
            for (int i = 0; i < 8; ++i) {
                u16 h0 = f2bu(v[2*i]),   h1 = f2bu(v[2*i+1]);
                u16 l0 = f2bu(v[2*i] - bu2f(h0)), l1 = f2bu(v[2*i+1] - bu2f(h1));
                hp[i] = (unsigned)h0 | ((unsigned)h1 << 16);
                lp[i] = (unsigned)l0 | ((unsigned)l1 << 16);
            }
            uint4* dh = (uint4*)(xs_hi + row * 264 + kb);
            uint4* dl = (uint4*)(xs_lo + row * 264 + kb);
            dh[0] = (uint4){hp[0], hp[1], hp[2], hp[3]};
            dh[1] = (uint4){hp[4], hp[5], hp[6], hp[7]};
            dl[0] = (uint4){lp[0], lp[1], lp[2], lp[3]};
            dl[1] = (uint4){lp[4], lp[5], lp[6], lp[7]};
        }
        // ---------- phase B: 8 k-chunks, async dbuf, 4 MFMA/chunk/wave ------
        const u16* Wtl = Wt + (size_t)layer * 65536;
        {   // stage chunk 0 into half 0
            #pragma unroll
            for (int j = 0; j < 2; ++j) {
                int dest = (w * 2 + j) * 2048 + lane * 16;
                int nl = (w * 2 + j) * 32 + (lane >> 2);
                const char* src = (const char*)(Wtl + (size_t)(n0 + nl) * 256 + (lane & 3) * 8);
                async16(src, wbB + dest);
            }
        }
        f32x4 ac0 = {0.f, 0.f, 0.f, 0.f}, ac1 = {0.f, 0.f, 0.f, 0.f};
        for (int c = 0; c < 8; ++c) {
            __syncthreads();          // drains stage(c); xs visible on c==0
            if (c < 7) {
                #pragma unroll
                for (int j = 0; j < 2; ++j) {
                    int dest = (((c + 1) & 1) * 8192) + (w * 2 + j) * 2048 + lane * 16;
                    int nl = (w * 2 + j) * 32 + (lane >> 2);
                    const char* src = (const char*)(Wtl + (size_t)(n0 + nl) * 256 +
                                                    (c + 1) * 32 + (lane & 3) * 8);
                    async16(src, wbB + dest);
                }
            }
            const u16* wb = (const u16*)(wbB + (c & 1) * 8192);
            s16x8 ah = *(const s16x8*)(xs_hi + l16 * 264 + c * 32 + quad * 8);
            s16x8 al = *(const s16x8*)(xs_lo + l16 * 264 + c * 32 + quad * 8);
            s16x8 b0 = *(const s16x8*)(wb + (w * 32 + l16) * 32 + quad * 8);
            s16x8 b1 = *(const s16x8*)(wb + (w * 32 + 16 + l16) * 32 + quad * 8);
            ac0 = mfma16(ah, b0, ac0);
            ac0 = mfma16(al, b0, ac0);
            ac1 = mfma16(ah, b1, ac1);
            ac1 = mfma16(al, b1, ac1);
        }
        // ---------- epilogue: s1/s2 partials + h store ----------
        const __hip_bfloat16* gab = (const __hip_bfloat16*)gat_a + (size_t)layer * 512;
        int c0 = n0 + w * 32 + l16, c1 = c0 + 16;
        float a10 = b2f(gab[c0]), a11 = b2f(gab[c1]);
        float a20 = b2f(gab[256 + c0]), a21 = b2f(gab[256 + c1]);
        float p1[4], p2[4];
        #pragma unroll
        for (int r = 0; r < 4; ++r) {
            p1[r] = ac0[r] * a10 + ac1[r] * a11;
            p2[r] = ac0[r] * a20 + ac1[r] * a21;
            #pragma unroll
            for (int off = 1; off < 16; off <<= 1) {
                p1[r] += __shfl_xor(p1[r], off, 64);
                p2[r] += __shfl_xor(p2[r], off, 64);
            }
        }
        if (l16 == 0) {
            #pragma unroll
            for (int r = 0; r < 4; ++r) {
                sred[w * 16 + quad * 4 + r] = p1[r];
                sred[64 + w * 16 + quad * 4 + r] = p2[r];
            }
        }
        #pragma unroll
        for (int r = 0; r < 4; ++r) {
            int gr = row0 + quad * 4 + r;
            h[(size_t)gr * 256 + n0 + w * 32 + l16]      = ac0[r];
            h[(size_t)gr * 256 + n0 + w * 32 + 16 + l16] = ac1[r];
        }
        __syncthreads();
        if (t < 16) {
            sp1[nh * 4096 + row0 + t] = sred[t] + sred[16 + t] + sred[32 + t] + sred[48 + t];
            sp2[nh * 4096 + row0 + t] = sred[64 + t] + sred[80 + t] + sred[96 + t] + sred[112 + t];
        }
    } else {
        // ---------------- f32 fallback (correct, unoptimized) ----------------
        float* xsf = (float*)smem;                 // [16][256]
        const float* Wl = (const float*)gat_W_raw + (size_t)layer * 65536;
        const float* gaf = (const float*)gat_a + (size_t)layer * 512;
        if (first) {
            float* nfsf = (float*)(smem + 16896);  // [16][80]
            const float* nff = (const float*)nf;
            for (int i = t; i < 16 * 78; i += 256) {
                int r = i / 78, k = i - r * 78;
                nfsf[r * 80 + k] = nff[(row0 + r) * 78 + k];
            }
            __syncthreads();
            int row = t >> 4, cb = (t & 15) * 16;
            const float* Wnf = (const float*)Wn_raw;
            const float* bnf = (const float*)bn;
            float acc[16];
            #pragma unroll
            for (int j = 0; j < 16; ++j) acc[j] = bnf[cb + j];
            for (int k = 0; k < 78; ++k) {
                float xv = nfsf[row * 80 + k];
                #pragma unroll
                for (int j = 0; j < 16; ++j) acc[j] += xv * Wnf[k * 256 + cb + j];
            }
            #pragma unroll
            for (int j = 0; j < 16; ++j) xsf[row * 256 + cb + j] = acc[j];
            __syncthreads();
        } else {
            for (int i = t; i < 16 * 64; i += 256) {
                int r = i >> 6, c4 = i & 63;
                ((float4*)(xsf + r * 256))[c4] =
                    ((const float4*)(x + (size_t)(row0 + r) * 256))[c4];
            }
            __syncthreads();
        }
        int ty = t >> 4, col0 = n0 + (t & 15) * 8;
        float acc[8];
        #pragma unroll
        for (int j = 0; j < 8; ++j) acc[j] = 0.f;
        for (int k = 0; k < 256; ++k) {
            float xv = xsf[ty * 256 + k];
            float w8[8]; ld8f(Wl + k * 256 + col0, w8);
            #pragma unroll
            for (int j = 0; j < 8; ++j) acc[j] += xv * w8[j];
        }
        float d1 = 0.f, d2 = 0.f;
        #pragma unroll
        for (int j = 0; j < 8; ++j) {
            d1 += acc[j] * gaf[col0 + j];
            d2 += acc[j] * gaf[256 + col0 + j];
        }
        #pragma unroll
        for (int off = 1; off < 16; off <<= 1) {
            d1 += __shfl_xor(d1, off, 64);
            d2 += __shfl_xor(d2, off, 64);
        }
        if ((lane & 15) == 0) { sred[ty] = d1; sred[32 + ty] = d2; }
        #pragma unroll
        for (int j = 0; j < 8; ++j) h[(size_t)(row0 + ty) * 256 + col0 + j] = acc[j];
        __syncthreads();
        if (t < 16) {
            sp1[nh * 4096 + row0 + t] = sred[t];
            sp2[nh * 4096 + row0 + t] = sred[32 + t];
        }
    }
}

// ---------------- attn: softmax(mask(leaky(s1+s2))) @ h ---------------------
__global__ __launch_bounds__(256) void k_attn(
    const float* __restrict__ h, const float* __restrict__ sp1,
    const float* __restrict__ sp2, const int* __restrict__ adj,
    float* __restrict__ x, float* __restrict__ gpart, int do_pool) {
    __shared__ float att_t[128][10];
    __shared__ __align__(16) float hbuf[2][32 * 256];
    __shared__ float pool_red[4][256];
    int blk = blockIdx.x, b = blk >> 4, i0 = (blk & 15) << 3;
    int t = threadIdx.x, w = t >> 6, lane = t & 63;
    const char* hbytes = (const char*)(h + (size_t)b * 32768);
    const int ph = blk & 3;
    {
        char* lb = (char*)&hbuf[0][0];
        const char* g = hbytes + ph * 32768;
        #pragma unroll
        for (int i = 0; i < 8; ++i)
            async16(g + i * 4096 + t * 16, lb + i * 4096 + t * 16);
    }
    {
        int c0 = lane, c1 = lane + 64;
        int ir0 = i0 + 2 * w, ir1 = ir0 + 1;
        const int* a0 = adj + (size_t)(b * 128 + ir0) * 128;
        const int* a1 = adj + (size_t)(b * 128 + ir1) * 128;
        int m00 = a0[c0], m01 = a0[c1], m10 = a1[c0], m11 = a1[c1];
        float sv0 = sp1[b * 128 + ir0] + sp1[4096 + b * 128 + ir0];
        float sv1 = sp1[b * 128 + ir1] + sp1[4096 + b * 128 + ir1];
        float t0 = sp2[b * 128 + c0] + sp2[4096 + b * 128 + c0];
        float t1 = sp2[b * 128 + c1] + sp2[4096 + b * 128 + c1];
        float e00 = sv0 + t0; e00 = (e00 >= 0.f) ? e00 : 0.2f * e00;
        float e01 = sv0 + t1; e01 = (e01 >= 0.f) ? e01 : 0.2f * e01;
        float e10 = sv1 + t0; e10 = (e10 >= 0.f) ? e10 : 0.2f * e10;
        float e11 = sv1 + t1; e11 = (e11 >= 0.f) ? e11 : 0.2f * e11;
        float v00 = (m00 > 0) ? e00 : NEG_INF;
        float v01 = (m01 > 0) ? e01 : NEG_INF;
        float v10 = (m10 > 0) ? e10 : NEG_INF;
        float v11 = (m11 > 0) ? e11 : NEG_INF;
        float mx0 = fmaxf(v00, v01), mx1 = fmaxf(v10, v11);
        #pragma unroll
        for (int off = 1; off < 64; off <<= 1) {
            mx0 = fmaxf(mx0, __shfl_xor(mx0, off, 64));
            mx1 = fmaxf(mx1, __shfl_xor(mx1, off, 64));
        }
        float p00 = __expf(v00 - mx0), p01 = __expf(v01 - mx0);
        float p10 = __expf(v10 - mx1), p11 = __expf(v11 - mx1);
        float s0 = p00 + p01, ss1 = p10 + p11;
        #pragma unroll
        for (int off = 1; off < 64; off <<= 1) {
            s0  += __shfl_xor(s0, off, 64);
            ss1 += __shfl_xor(ss1, off, 64);
        }
        float inv0 = 1.0f / s0, inv1 = 1.0f / ss1;
        att_t[c0][2 * w]     = p00 * inv0;
        att_t[c1][2 * w]     = p01 * inv0;
        att_t[c0][2 * w + 1] = p10 * inv1;
        att_t[c1][2 * w + 1] = p11 * inv1;
    }
    __syncthreads();
    int tx = t & 63, ty = t >> 6;
    float acc0[4] = {0.f, 0.f, 0.f, 0.f}, acc1[4] = {0.f, 0.f, 0.f, 0.f};
    for (int c = 0; c < 4; ++c) {
        if (c < 3) {
            char* lb = (char*)&hbuf[(c + 1) & 1][0];
            const char* g = hbytes + (((c + 1 + ph) & 3) * 32768);
            #pragma unroll
            for (int i = 0; i < 8; ++i)
                async16(g + i * 4096 + t * 16, lb + i * 4096 + t * 16);
        }
        const float* hc = &hbuf[c & 1][0];
        const int jb = ((c + ph) & 3) * 32;
        #pragma unroll 4
        for (int jj = 0; jj < 32; ++jj) {
            float4 hv = *(const float4*)&hc[jj * 256 + 4 * tx];
            float2 ap = *(const float2*)&att_t[jb + jj][2 * ty];
            acc0[0] += ap.x * hv.x; acc0[1] += ap.x * hv.y;
            acc0[2] += ap.x * hv.z; acc0[3] += ap.x * hv.w;
            acc1[0] += ap.y * hv.x; acc1[1] += ap.y * hv.y;
            acc1[2] += ap.y * hv.z; acc1[3] += ap.y * hv.w;
        }
        __syncthreads();
    }
    if (!do_pool) {
        float4 o0 = {fmaxf(acc0[0],0.f), fmaxf(acc0[1],0.f), fmaxf(acc0[2],0.f), fmaxf(acc0[3],0.f)};
        float4 o1 = {fmaxf(acc1[0],0.f), fmaxf(acc1[1],0.f), fmaxf(acc1[2],0.f), fmaxf(acc1[3],0.f)};
        *(float4*)&x[(size_t)(b * 128 + i0 + 2 * ty)     * 256 + 4 * tx] = o0;
        *(float4*)&x[(size_t)(b * 128 + i0 + 2 * ty + 1) * 256 + 4 * tx] = o1;
    } else {
        float4 pr = {(fmaxf(acc0[0],0.f) + fmaxf(acc1[0],0.f)) * (1.f/128.f),
                     (fmaxf(acc0[1],0.f) + fmaxf(acc1[1],0.f)) * (1.f/128.f),
                     (fmaxf(acc0[2],0.f) + fmaxf(acc1[2],0.f)) * (1.f/128.f),
                     (fmaxf(acc0[3],0.f) + fmaxf(acc1[3],0.f)) * (1.f/128.f)};
        *(float4*)&pool_red[ty][4 * tx] = pr;
        __syncthreads();
        if (t < 64) {
            float4 r0 = ((const float4*)&pool_red[0][0])[t];
            float4 r1 = ((const float4*)&pool_red[1][0])[t];
            float4 r2 = ((const float4*)&pool_red[2][0])[t];
            float4 r3 = ((const float4*)&pool_red[3][0])[t];
            float4 o = {r0.x+r1.x+r2.x+r3.x, r0.y+r1.y+r2.y+r3.y,
                        r0.z+r1.z+r2.z+r3.z, r0.w+r1.w+r2.w+r3.w};
            *(float4*)&gpart[((size_t)b * 16 + (blk & 15)) * 256 + 4 * t] = o;
        }
    }
}

// ---------------- head: pool MLPs + concat + out MLP ------------------------
template <typename T>
__device__ __forceinline__ void head_body(
    int b, int t, const float* __restrict__ gpart,
    const T* scaf, const T* W_sc, const T* b_sc,
    const T* gp_w1, const T* gp_b1, const T* gp_w2, const T* gp_b2,
    const T* out_w1, const T* out_b1, const T* out_w2, const T* out_b2,
    float* gin_s, float* sproj, float* scaf_s,
    float* red1, float* red2, float* z1g, float* z1s,
    float* cvec, float* hdn, float* outv) {
    float g = 0.f;
    #pragma unroll
    for (int gg = 0; gg < 16; ++gg) g += gpart[((size_t)b * 16 + gg) * 256 + t];
    gin_s[t] = g;
    if (t < 20) scaf_s[t] = ldv(scaf, b * 20 + t);
    __syncthreads();
    {
        float sa = ldv(b_sc, t);
        #pragma unroll
        for (int k = 0; k < 20; ++k) sa += scaf_s[k] * ldv(W_sc, k * 256 + t);
        sproj[t] = sa;
    }
    __syncthreads();
    {
        int j = t & 127, khalf = t >> 7;
        int k0 = khalf * 128;
        float a1 = 0.f, a2 = 0.f;
        #pragma unroll 16
        for (int kk = 0; kk < 128; ++kk) {
            int k = k0 + kk;
            float wv = ldv(gp_w1, k * 128 + j);
            a1 += gin_s[k] * wv;
            a2 += sproj[k] * wv;
        }
        red1[t] = a1; red2[t] = a2;
    }
    __syncthreads();
    if (t < 128) {
        float bb = ldv(gp_b1, t);
        z1g[t] = fmaxf(bb + red1[t] + red1[t + 128], 0.f);
        z1s[t] = fmaxf(bb + red2[t] + red2[t + 128], 0.f);
    }
    __syncthreads();
    {
        int j = t & 63, q = t >> 6;
        int k0 = q * 32;
        float a1 = 0.f, a2 = 0.f;
        #pragma unroll
        for (int kk = 0; kk < 32; ++kk) {
            int k = k0 + kk;
            float wv = ldv(gp_w2, k * 64 + j);
            a1 += z1g[k] * wv;
            a2 += z1s[k] * wv;
        }
        red1[t] = a1; red2[t] = a2;
    }
    __syncthreads();
    if (t < 64) {
        float bb = ldv(gp_b2, t);
        cvec[t]      = fmaxf(bb + red1[t] + red1[t + 64] + red1[t + 128] + red1[t + 192], 0.f);
        cvec[64 + t] = fmaxf(bb + red2[t] + red2[t + 64] + red2[t + 128] + red2[t + 192], 0.f);
    }
    __syncthreads();
    {
        int j = t & 127, khalf = t >> 7;
        int k0 = khalf * 64;
        float a = 0.f;
        #pragma unroll 16
        for (int kk = 0; kk < 64; ++kk) {
            int k = k0 + kk;
            a += cvec[k] * ldv(out_w1, k * 128 + j);
        }
        red1[t] = a;
    }
    __syncthreads();
    if (t < 128) hdn[t] = fmaxf(ldv(out_b1, t) + red1[t] + red1[t + 128], 0.f);
    __syncthreads();
    if (t < 13) {
        float a = ldv(out_b2, t);
        #pragma unroll 16
        for (int k = 0; k < 128; ++k) a += hdn[k] * ldv(out_w2, k * 13 + t);
        outv[t] = a;
    }
}

__global__ __launch_bounds__(256) void k_head(
    const float* __restrict__ gpart, const void* __restrict__ scaf,
    const void* __restrict__ W_sc, const void* __restrict__ b_sc,
    const void* __restrict__ gp_w1, const void* __restrict__ gp_b1,
    const void* __restrict__ gp_w2, const void* __restrict__ gp_b2,
    const void* __restrict__ out_w1, const void* __restrict__ out_b1,
    const void* __restrict__ out_w2, const void* __restrict__ out_b2,
    void* __restrict__ out, const void* __restrict__ Wn) {
    int isbf = sniff(Wn);
    int b = blockIdx.x;
    int t = threadIdx.x;
    __shared__ float gin_s[256], sproj[256], scaf_s[20];
    __shared__ float red1[256], red2[256];
    __shared__ float z1g[128], z1s[128], cvec[128], hdn[128], outv[13];
    if (isbf) {
        head_body<__hip_bfloat16>(b, t, gpart,
            (const __hip_bfloat16*)scaf, (const __hip_bfloat16*)W_sc, (const __hip_bfloat16*)b_sc,
            (const __hip_bfloat16*)gp_w1, (const __hip_bfloat16*)gp_b1,
            (const __hip_bfloat16*)gp_w2, (const __hip_bfloat16*)gp_b2,
            (const __hip_bfloat16*)out_w1, (const __hip_bfloat16*)out_b1,
            (const __hip_bfloat16*)out_w2, (const __hip_bfloat16*)out_b2,
            gin_s, sproj, scaf_s, red1, red2, z1g, z1s, cvec, hdn, outv);
    } else {
        head_body<float>(b, t, gpart,
            (const float*)scaf, (const float*)W_sc, (const float*)b_sc,
            (const float*)gp_w1, (const float*)gp_b1,
            (const float*)gp_w2, (const float*)gp_b2,
            (const float*)out_w1, (const float*)out_b1,
            (const float*)out_w2, (const float*)out_b2,
            gin_s, sproj, scaf_s, red1, red2, z1g, z1s, cvec, hdn, outv);
    }
    __syncthreads();
    if (t < 13) {
        if (isbf) ((__hip_bfloat16*)out)[b * 13 + t] = __float2bfloat16(outv[t]);
        else      ((float*)out)[b * 13 + t] = outv[t];
    }
}

extern "C" void kernel_launch(void* const* d_in, const int* in_sizes, int n_in,
                              void* d_out, int out_size, void* d_ws, size_t ws_size,
                              hipStream_t stream) {
    (void)in_sizes; (void)n_in; (void)out_size; (void)ws_size;
    const void* nf     = d_in[0];
    const int*  adj    = (const int*)d_in[2];
    const void* scaf   = d_in[3];
    const void* W_node = d_in[4];
    const void* b_node = d_in[5];
    const void* gat_W  = d_in[6];
    const void* gat_a  = d_in[7];
    const void* W_sc   = d_in[8];
    const void* b_sc   = d_in[9];
    const void* gp_w1  = d_in[10];
    const void* gp_b1  = d_in[11];
    const void* gp_w2  = d_in[12];
    const void* gp_b2  = d_in[13];
    const void* out_w1 = d_in[14];
    const void* out_b1 = d_in[15];
    const void* out_w2 = d_in[16];
    const void* out_b2 = d_in[17];

    float* ws    = (float*)d_ws;
    float* x     = ws;                     // 1048576
    float* h     = ws + 1048576;           // 1048576
    float* sp1   = ws + 2097152;           // 8192 (two halves of 4096)
    float* sp2   = sp1 + 8192;             // 8192
    float* gpart = sp2 + 8192;             // 131072
    u16*   Wt    = (u16*)(gpart + 131072); // 3*65536 u16
    u16*   Wnt   = Wt + 196608;            // 256*96 u16

    k_wt<<<26, 256, 0, stream>>>(gat_W, W_node, Wt, Wnt);
    for (int l = 0; l < 3; ++l) {
        k_gat<<<512, 256, 0, stream>>>(x, Wt, gat_W, gat_a, l,
                                       nf, Wnt, W_node, b_node, (l == 0) ? 1 : 0,
                                       h, sp1, sp2);
        k_attn<<<512, 256, 0, stream>>>(h, sp1, sp2, adj, x, gpart, (l == 2) ? 1 : 0);
    }
    k_head<<<32, 256, 0, stream>>>(gpart, scaf, W_sc, b_sc, gp_w1, gp_b1, gp_w2, gp_b2,
                                   out_w1, out_b1, out_w2, out_b2, d_out, W_node);
}

// Round 9
// 227.158 us; speedup vs baseline: 1.2553x; 1.2553x over previous
//
#include <hip/hip_runtime.h>
#include <hip/hip_bf16.h>

#define NEG_INF -9.0e15f

using u16 = unsigned short;

__device__ __forceinline__ float b2f(__hip_bfloat16 v) { return __bfloat162float(v); }
__device__ __forceinline__ float ldv(const float* p, int i) { return p[i]; }
__device__ __forceinline__ float ldv(const __hip_bfloat16* p, int i) { return __bfloat162float(p[i]); }

__device__ __forceinline__ void async16(const void* g, void* l) {
    __builtin_amdgcn_global_load_lds(
        (__attribute__((address_space(1))) void*)(g),
        (__attribute__((address_space(3))) void*)(l), 16, 0, 0);
}

// wave-level dtype sniff (uniform per wave): bf16 weights -> sane exponents.
__device__ __forceinline__ int sniff(const void* wnode) {
    const u16* w = (const u16*)wnode;
    int lane = threadIdx.x & 63;
    u16 u = w[2 * lane];
    int e = (u >> 7) & 0xFF;
    unsigned long long m = __ballot(e >= 100 && e <= 140);
    return __popcll(m) >= 48;
}

// -------- k_rep: replicate gat_W and W_node x8 to split L2 line sharing ----
__global__ __launch_bounds__(256) void k_rep(
    const void* __restrict__ gat_W, const void* __restrict__ W_node,
    u16* __restrict__ Wrep, u16* __restrict__ Wnrep) {
    if (!sniff(W_node)) return;    // f32 path reads originals
    int b = blockIdx.x, t = threadIdx.x;
    if (b < 384) {                 // 8 copies x 48 blocks x 256 uint4 = 12288/copy
        int c = b / 48, idx = (b % 48) * 256 + t;
        ((uint4*)(Wrep + (size_t)c * 196608))[idx] = ((const uint4*)gat_W)[idx];
    } else {
        int bb = b - 384;          // 8 copies x 5 blocks; 1248 uint4/copy
        int c = bb / 5, idx = (bb % 5) * 256 + t;
        if (idx < 1248)
            ((uint4*)(Wnrep + (size_t)c * 19968))[idx] = ((const uint4*)W_node)[idx];
    }
}

// -------- k_gat: h = x@W[l]; s1 = h@a1; s2 = h@a2 -- attn-mirror shape -----
// 512 blocks x 256 thr. Block = 8 rows x 256 cols. Thread: rows {2w,2w+1}
// (w = wave = t>>6), cols 4tx..4tx+3 (tx = t&63). W direct from global
// (replicated copy bx&7), x broadcast from stride-10 LDS transpose.
// No barriers inside the k-loop.
__global__ __launch_bounds__(256) void k_gat(
    const float* __restrict__ x, const void* __restrict__ gat_W,
    const u16* __restrict__ Wrep, const void* __restrict__ gat_a, int layer,
    const void* __restrict__ nf, const void* __restrict__ Wn_raw,
    const u16* __restrict__ Wnrep, const void* __restrict__ bn, int first,
    float* __restrict__ h, float* __restrict__ s1, float* __restrict__ s2) {
    __shared__ float xsT[256 * 10];     // [k][row(8) pad 10]
    const int t = threadIdx.x;
    const int bx = blockIdx.x;
    const int row0 = bx * 8;
    const int tx = t & 63, w = t >> 6;  // wave w handles rows 2w, 2w+1
    const int isbf = sniff(Wn_raw);
    const int c0 = 4 * tx;

    float acc0[4], acc1[4];

    if (isbf) {
        if (first) {
            // stage nf rows transposed: nfsT[k][r] (reuse xsT, k<78)
            const u16* nfu = (const u16*)nf;
            for (int i = t; i < 624; i += 256) {
                int r = i / 78, k = i - r * 78;
                xsT[k * 10 + r] = __uint_as_float(((unsigned)nfu[(row0 + r) * 78 + k]) << 16);
            }
            __syncthreads();
            const u16* Wnl = Wnrep + (size_t)(bx & 7) * 19968;
            const __hip_bfloat16* bnb = (const __hip_bfloat16*)bn;
            #pragma unroll
            for (int j = 0; j < 4; ++j) { acc0[j] = b2f(bnb[c0 + j]); acc1[j] = acc0[j]; }
            #pragma unroll 2
            for (int k = 0; k < 78; ++k) {
                uint2 wv = *(const uint2*)(Wnl + k * 256 + c0);
                float w0 = __uint_as_float(wv.x << 16);
                float w1 = __uint_as_float(wv.x & 0xffff0000u);
                float w2 = __uint_as_float(wv.y << 16);
                float w3 = __uint_as_float(wv.y & 0xffff0000u);
                float2 xp = *(const float2*)&xsT[k * 10 + 2 * w];
                acc0[0] += xp.x * w0; acc0[1] += xp.x * w1;
                acc0[2] += xp.x * w2; acc0[3] += xp.x * w3;
                acc1[0] += xp.y * w0; acc1[1] += xp.y * w1;
                acc1[2] += xp.y * w2; acc1[3] += xp.y * w3;
            }
            __syncthreads();   // done reading nf variant of xsT
            // scatter x0 into xsT[k][row]
            #pragma unroll
            for (int j = 0; j < 4; ++j) {
                xsT[(c0 + j) * 10 + 2 * w]     = acc0[j];
                xsT[(c0 + j) * 10 + 2 * w + 1] = acc1[j];
            }
            __syncthreads();
        } else {
            // stage x rows transposed: thread reads 8 consecutive floats of one row
            int r = t >> 5, cb = (t & 31) * 8;
            const float4* xp = (const float4*)(x + (size_t)(row0 + r) * 256 + cb);
            float4 f0 = xp[0], f1 = xp[1];
            xsT[(cb + 0) * 10 + r] = f0.x; xsT[(cb + 1) * 10 + r] = f0.y;
            xsT[(cb + 2) * 10 + r] = f0.z; xsT[(cb + 3) * 10 + r] = f0.w;
            xsT[(cb + 4) * 10 + r] = f1.x; xsT[(cb + 5) * 10 + r] = f1.y;
            xsT[(cb + 6) * 10 + r] = f1.z; xsT[(cb + 7) * 10 + r] = f1.w;
            __syncthreads();
        }
        // main k-loop: barrier-free, direct global W (replica bx&7)
        const u16* Wl = Wrep + (size_t)(bx & 7) * 196608 + (size_t)layer * 65536;
        #pragma unroll
        for (int j = 0; j < 4; ++j) { acc0[j] = 0.f; acc1[j] = 0.f; }
        #pragma unroll 4
        for (int k = 0; k < 256; ++k) {
            uint2 wv = *(const uint2*)(Wl + k * 256 + c0);
            float w0 = __uint_as_float(wv.x << 16);
            float w1 = __uint_as_float(wv.x & 0xffff0000u);
            float w2 = __uint_as_float(wv.y << 16);
            float w3 = __uint_as_float(wv.y & 0xffff0000u);
            float2 xp = *(const float2*)&xsT[k * 10 + 2 * w];
            acc0[0] += xp.x * w0; acc0[1] += xp.x * w1;
            acc0[2] += xp.x * w2; acc0[3] += xp.x * w3;
            acc1[0] += xp.y * w0; acc1[1] += xp.y * w1;
            acc1[2] += xp.y * w2; acc1[3] += xp.y * w3;
        }
        // epilogue: s1/s2 (full-wave reduce; wave = exactly rows 2w,2w+1)
        const __hip_bfloat16* ga = (const __hip_bfloat16*)gat_a + (size_t)layer * 512;
        float d10 = 0.f, d20 = 0.f, d11 = 0.f, d21 = 0.f;
        #pragma unroll
        for (int j = 0; j < 4; ++j) {
            float a1v = b2f(ga[c0 + j]), a2v = b2f(ga[256 + c0 + j]);
            d10 += acc0[j] * a1v; d20 += acc0[j] * a2v;
            d11 += acc1[j] * a1v; d21 += acc1[j] * a2v;
        }
        #pragma unroll
        for (int off = 1; off < 64; off <<= 1) {
            d10 += __shfl_xor(d10, off, 64); d20 += __shfl_xor(d20, off, 64);
            d11 += __shfl_xor(d11, off, 64); d21 += __shfl_xor(d21, off, 64);
        }
        if (tx == 0) {
            s1[row0 + 2 * w] = d10;     s2[row0 + 2 * w] = d20;
            s1[row0 + 2 * w + 1] = d11; s2[row0 + 2 * w + 1] = d21;
        }
        *(float4*)&h[(size_t)(row0 + 2 * w) * 256 + c0]     = (float4){acc0[0], acc0[1], acc0[2], acc0[3]};
        *(float4*)&h[(size_t)(row0 + 2 * w + 1) * 256 + c0] = (float4){acc1[0], acc1[1], acc1[2], acc1[3]};
    } else {
        // ---------------- f32 fallback (correct, unoptimized) ----------------
        const float* Wlf = (const float*)gat_W + (size_t)layer * 65536;
        const float* gaf = (const float*)gat_a + (size_t)layer * 512;
        if (first) {
            const float* nff = (const float*)nf;
            for (int i = t; i < 624; i += 256) {
                int r = i / 78, k = i - r * 78;
                xsT[k * 10 + r] = nff[(row0 + r) * 78 + k];
            }
            __syncthreads();
            const float* Wnf = (const float*)Wn_raw;
            const float* bnf = (const float*)bn;
            #pragma unroll
            for (int j = 0; j < 4; ++j) { acc0[j] = bnf[c0 + j]; acc1[j] = acc0[j]; }
            for (int k = 0; k < 78; ++k) {
                float4 wf = *(const float4*)(Wnf + k * 256 + c0);
                float2 xp = *(const float2*)&xsT[k * 10 + 2 * w];
                acc0[0] += xp.x * wf.x; acc0[1] += xp.x * wf.y;
                acc0[2] += xp.x * wf.z; acc0[3] += xp.x * wf.w;
                acc1[0] += xp.y * wf.x; acc1[1] += xp.y * wf.y;
                acc1[2] += xp.y * wf.z; acc1[3] += xp.y * wf.w;
            }
            __syncthreads();
            #pragma unroll
            for (int j = 0; j < 4; ++j) {
                xsT[(c0 + j) * 10 + 2 * w]     = acc0[j];
                xsT[(c0 + j) * 10 + 2 * w + 1] = acc1[j];
            }
            __syncthreads();
        } else {
            int r = t >> 5, cb = (t & 31) * 8;
            const float4* xp = (const float4*)(x + (size_t)(row0 + r) * 256 + cb);
            float4 f0 = xp[0], f1 = xp[1];
            xsT[(cb + 0) * 10 + r] = f0.x; xsT[(cb + 1) * 10 + r] = f0.y;
            xsT[(cb + 2) * 10 + r] = f0.z; xsT[(cb + 3) * 10 + r] = f0.w;
            xsT[(cb + 4) * 10 + r] = f1.x; xsT[(cb + 5) * 10 + r] = f1.y;
            xsT[(cb + 6) * 10 + r] = f1.z; xsT[(cb + 7) * 10 + r] = f1.w;
            __syncthreads();
        }
        #pragma unroll
        for (int j = 0; j < 4; ++j) { acc0[j] = 0.f; acc1[j] = 0.f; }
        #pragma unroll 4
        for (int k = 0; k < 256; ++k) {
            float4 wf = *(const float4*)(Wlf + k * 256 + c0);
            float2 xp = *(const float2*)&xsT[k * 10 + 2 * w];
            acc0[0] += xp.x * wf.x; acc0[1] += xp.x * wf.y;
            acc0[2] += xp.x * wf.z; acc0[3] += xp.x * wf.w;
            acc1[0] += xp.y * wf.x; acc1[1] += xp.y * wf.y;
            acc1[2] += xp.y * wf.z; acc1[3] += xp.y * wf.w;
        }
        float d10 = 0.f, d20 = 0.f, d11 = 0.f, d21 = 0.f;
        #pragma unroll
        for (int j = 0; j < 4; ++j) {
            float a1v = gaf[c0 + j], a2v = gaf[256 + c0 + j];
            d10 += acc0[j] * a1v; d20 += acc0[j] * a2v;
            d11 += acc1[j] * a1v; d21 += acc1[j] * a2v;
        }
        #pragma unroll
        for (int off = 1; off < 64; off <<= 1) {
            d10 += __shfl_xor(d10, off, 64); d20 += __shfl_xor(d20, off, 64);
            d11 += __shfl_xor(d11, off, 64); d21 += __shfl_xor(d21, off, 64);
        }
        if (tx == 0) {
            s1[row0 + 2 * w] = d10;     s2[row0 + 2 * w] = d20;
            s1[row0 + 2 * w + 1] = d11; s2[row0 + 2 * w + 1] = d21;
        }
        *(float4*)&h[(size_t)(row0 + 2 * w) * 256 + c0]     = (float4){acc0[0], acc0[1], acc0[2], acc0[3]};
        *(float4*)&h[(size_t)(row0 + 2 * w + 1) * 256 + c0] = (float4){acc1[0], acc1[1], acc1[2], acc1[3]};
    }
}

// ---------------- attn: softmax(mask(leaky(s1+s2))) @ h ---------------------
__global__ __launch_bounds__(256) void k_attn(
    const float* __restrict__ h, const float* __restrict__ s1,
    const float* __restrict__ s2, const int* __restrict__ adj,
    float* __restrict__ x, float* __restrict__ gpart, int do_pool) {
    __shared__ float att_t[128][10];
    __shared__ __align__(16) float hbuf[2][32 * 256];
    __shared__ float pool_red[4][256];
    int blk = blockIdx.x, b = blk >> 4, i0 = (blk & 15) << 3;
    int t = threadIdx.x, w = t >> 6, lane = t & 63;
    const char* hbytes = (const char*)(h + (size_t)b * 32768);
    const int ph = blk & 3;
    {
        char* lb = (char*)&hbuf[0][0];
        const char* g = hbytes + ph * 32768;
        #pragma unroll
        for (int i = 0; i < 8; ++i)
            async16(g + i * 4096 + t * 16, lb + i * 4096 + t * 16);
    }
    {
        int cc0 = lane, cc1 = lane + 64;
        int ir0 = i0 + 2 * w, ir1 = ir0 + 1;
        const int* a0 = adj + (size_t)(b * 128 + ir0) * 128;
        const int* a1 = adj + (size_t)(b * 128 + ir1) * 128;
        int m00 = a0[cc0], m01 = a0[cc1], m10 = a1[cc0], m11 = a1[cc1];
        float sv0 = s1[b * 128 + ir0], sv1 = s1[b * 128 + ir1];
        float t0 = s2[b * 128 + cc0],  t1 = s2[b * 128 + cc1];
        float e00 = sv0 + t0; e00 = (e00 >= 0.f) ? e00 : 0.2f * e00;
        float e01 = sv0 + t1; e01 = (e01 >= 0.f) ? e01 : 0.2f * e01;
        float e10 = sv1 + t0; e10 = (e10 >= 0.f) ? e10 : 0.2f * e10;
        float e11 = sv1 + t1; e11 = (e11 >= 0.f) ? e11 : 0.2f * e11;
        float v00 = (m00 > 0) ? e00 : NEG_INF;
        float v01 = (m01 > 0) ? e01 : NEG_INF;
        float v10 = (m10 > 0) ? e10 : NEG_INF;
        float v11 = (m11 > 0) ? e11 : NEG_INF;
        float mx0 = fmaxf(v00, v01), mx1 = fmaxf(v10, v11);
        #pragma unroll
        for (int off = 1; off < 64; off <<= 1) {
            mx0 = fmaxf(mx0, __shfl_xor(mx0, off, 64));
            mx1 = fmaxf(mx1, __shfl_xor(mx1, off, 64));
        }
        float p00 = __expf(v00 - mx0), p01 = __expf(v01 - mx0);
        float p10 = __expf(v10 - mx1), p11 = __expf(v11 - mx1);
        float s0 = p00 + p01, ss1 = p10 + p11;
        #pragma unroll
        for (int off = 1; off < 64; off <<= 1) {
            s0  += __shfl_xor(s0, off, 64);
            ss1 += __shfl_xor(ss1, off, 64);
        }
        float inv0 = 1.0f / s0, inv1 = 1.0f / ss1;
        att_t[cc0][2 * w]     = p00 * inv0;
        att_t[cc1][2 * w]     = p01 * inv0;
        att_t[cc0][2 * w + 1] = p10 * inv1;
        att_t[cc1][2 * w + 1] = p11 * inv1;
    }
    __syncthreads();
    int tx = t & 63, ty = t >> 6;
    float acc0[4] = {0.f, 0.f, 0.f, 0.f}, acc1[4] = {0.f, 0.f, 0.f, 0.f};
    for (int c = 0; c < 4; ++c) {
        if (c < 3) {
            char* lb = (char*)&hbuf[(c + 1) & 1][0];
            const char* g = hbytes + (((c + 1 + ph) & 3) * 32768);
            #pragma unroll
            for (int i = 0; i < 8; ++i)
                async16(g + i * 4096 + t * 16, lb + i * 4096 + t * 16);
        }
        const float* hc = &hbuf[c & 1][0];
        const int jb = ((c + ph) & 3) * 32;
        #pragma unroll 4
        for (int jj = 0; jj < 32; ++jj) {
            float4 hv = *(const float4*)&hc[jj * 256 + 4 * tx];
            float2 ap = *(const float2*)&att_t[jb + jj][2 * ty];
            acc0[0] += ap.x * hv.x; acc0[1] += ap.x * hv.y;
            acc0[2] += ap.x * hv.z; acc0[3] += ap.x * hv.w;
            acc1[0] += ap.y * hv.x; acc1[1] += ap.y * hv.y;
            acc1[2] += ap.y * hv.z; acc1[3] += ap.y * hv.w;
        }
        __syncthreads();
    }
    if (!do_pool) {
        float4 o0 = {fmaxf(acc0[0],0.f), fmaxf(acc0[1],0.f), fmaxf(acc0[2],0.f), fmaxf(acc0[3],0.f)};
        float4 o1 = {fmaxf(acc1[0],0.f), fmaxf(acc1[1],0.f), fmaxf(acc1[2],0.f), fmaxf(acc1[3],0.f)};
        *(float4*)&x[(size_t)(b * 128 + i0 + 2 * ty)     * 256 + 4 * tx] = o0;
        *(float4*)&x[(size_t)(b * 128 + i0 + 2 * ty + 1) * 256 + 4 * tx] = o1;
    } else {
        float4 pr = {(fmaxf(acc0[0],0.f) + fmaxf(acc1[0],0.f)) * (1.f/128.f),
                     (fmaxf(acc0[1],0.f) + fmaxf(acc1[1],0.f)) * (1.f/128.f),
                     (fmaxf(acc0[2],0.f) + fmaxf(acc1[2],0.f)) * (1.f/128.f),
                     (fmaxf(acc0[3],0.f) + fmaxf(acc1[3],0.f)) * (1.f/128.f)};
        *(float4*)&pool_red[ty][4 * tx] = pr;
        __syncthreads();
        if (t < 64) {
            float4 r0 = ((const float4*)&pool_red[0][0])[t];
            float4 r1 = ((const float4*)&pool_red[1][0])[t];
            float4 r2 = ((const float4*)&pool_red[2][0])[t];
            float4 r3 = ((const float4*)&pool_red[3][0])[t];
            float4 o = {r0.x+r1.x+r2.x+r3.x, r0.y+r1.y+r2.y+r3.y,
                        r0.z+r1.z+r2.z+r3.z, r0.w+r1.w+r2.w+r3.w};
            *(float4*)&gpart[((size_t)b * 16 + (blk & 15)) * 256 + 4 * t] = o;
        }
    }
}

// ---------------- head: pool MLPs + concat + out MLP ------------------------
template <typename T>
__device__ __forceinline__ void head_body(
    int b, int t, const float* __restrict__ gpart,
    const T* scaf, const T* W_sc, const T* b_sc,
    const T* gp_w1, const T* gp_b1, const T* gp_w2, const T* gp_b2,
    const T* out_w1, const T* out_b1, const T* out_w2, const T* out_b2,
    float* gin_s, float* sproj, float* scaf_s,
    float* red1, float* red2, float* z1g, float* z1s,
    float* cvec, float* hdn, float* outv) {
    float g = 0.f;
    #pragma unroll
    for (int gg = 0; gg < 16; ++gg) g += gpart[((size_t)b * 16 + gg) * 256 + t];
    gin_s[t] = g;
    if (t < 20) scaf_s[t] = ldv(scaf, b * 20 + t);
    __syncthreads();
    {
        float sa = ldv(b_sc, t);
        #pragma unroll
        for (int k = 0; k < 20; ++k) sa += scaf_s[k] * ldv(W_sc, k * 256 + t);
        sproj[t] = sa;
    }
    __syncthreads();
    {
        int j = t & 127, khalf = t >> 7;
        int k0 = khalf * 128;
        float a1 = 0.f, a2 = 0.f;
        #pragma unroll 16
        for (int kk = 0; kk < 128; ++kk) {
            int k = k0 + kk;
            float wv = ldv(gp_w1, k * 128 + j);
            a1 += gin_s[k] * wv;
            a2 += sproj[k] * wv;
        }
        red1[t] = a1; red2[t] = a2;
    }
    __syncthreads();
    if (t < 128) {
        float bb = ldv(gp_b1, t);
        z1g[t] = fmaxf(bb + red1[t] + red1[t + 128], 0.f);
        z1s[t] = fmaxf(bb + red2[t] + red2[t + 128], 0.f);
    }
    __syncthreads();
    {
        int j = t & 63, q = t >> 6;
        int k0 = q * 32;
        float a1 = 0.f, a2 = 0.f;
        #pragma unroll
        for (int kk = 0; kk < 32; ++kk) {
            int k = k0 + kk;
            float wv = ldv(gp_w2, k * 64 + j);
            a1 += z1g[k] * wv;
            a2 += z1s[k] * wv;
        }
        red1[t] = a1; red2[t] = a2;
    }
    __syncthreads();
    if (t < 64) {
        float bb = ldv(gp_b2, t);
        cvec[t]      = fmaxf(bb + red1[t] + red1[t + 64] + red1[t + 128] + red1[t + 192], 0.f);
        cvec[64 + t] = fmaxf(bb + red2[t] + red2[t + 64] + red2[t + 128] + red2[t + 192], 0.f);
    }
    __syncthreads();
    {
        int j = t & 127, khalf = t >> 7;
        int k0 = khalf * 64;
        float a = 0.f;
        #pragma unroll 16
        for (int kk = 0; kk < 64; ++kk) {
            int k = k0 + kk;
            a += cvec[k] * ldv(out_w1, k * 128 + j);
        }
        red1[t] = a;
    }
    __syncthreads();
    if (t < 128) hdn[t] = fmaxf(ldv(out_b1, t) + red1[t] + red1[t + 128], 0.f);
    __syncthreads();
    if (t < 13) {
        float a = ldv(out_b2, t);
        #pragma unroll 16
        for (int k = 0; k < 128; ++k) a += hdn[k] * ldv(out_w2, k * 13 + t);
        outv[t] = a;
    }
}

__global__ __launch_bounds__(256) void k_head(
    const float* __restrict__ gpart, const void* __restrict__ scaf,
    const void* __restrict__ W_sc, const void* __restrict__ b_sc,
    const void* __restrict__ gp_w1, const void* __restrict__ gp_b1,
    const void* __restrict__ gp_w2, const void* __restrict__ gp_b2,
    const void* __restrict__ out_w1, const void* __restrict__ out_b1,
    const void* __restrict__ out_w2, const void* __restrict__ out_b2,
    void* __restrict__ out, const void* __restrict__ Wn) {
    int isbf = sniff(Wn);
    int b = blockIdx.x;
    int t = threadIdx.x;
    __shared__ float gin_s[256], sproj[256], scaf_s[20];
    __shared__ float red1[256], red2[256];
    __shared__ float z1g[128], z1s[128], cvec[128], hdn[128], outv[13];
    if (isbf) {
        head_body<__hip_bfloat16>(b, t, gpart,
            (const __hip_bfloat16*)scaf, (const __hip_bfloat16*)W_sc, (const __hip_bfloat16*)b_sc,
            (const __hip_bfloat16*)gp_w1, (const __hip_bfloat16*)gp_b1,
            (const __hip_bfloat16*)gp_w2, (const __hip_bfloat16*)gp_b2,
            (const __hip_bfloat16*)out_w1, (const __hip_bfloat16*)out_b1,
            (const __hip_bfloat16*)out_w2, (const __hip_bfloat16*)out_b2,
            gin_s, sproj, scaf_s, red1, red2, z1g, z1s, cvec, hdn, outv);
    } else {
        head_body<float>(b, t, gpart,
            (const float*)scaf, (const float*)W_sc, (const float*)b_sc,
            (const float*)gp_w1, (const float*)gp_b1,
            (const float*)gp_w2, (const float*)gp_b2,
            (const float*)out_w1, (const float*)out_b1,
            (const float*)out_w2, (const float*)out_b2,
            gin_s, sproj, scaf_s, red1, red2, z1g, z1s, cvec, hdn, outv);
    }
    __syncthreads();
    if (t < 13) {
        if (isbf) ((__hip_bfloat16*)out)[b * 13 + t] = __float2bfloat16(outv[t]);
        else      ((float*)out)[b * 13 + t] = outv[t];
    }
}

extern "C" void kernel_launch(void* const* d_in, const int* in_sizes, int n_in,
                              void* d_out, int out_size, void* d_ws, size_t ws_size,
                              hipStream_t stream) {
    (void)in_sizes; (void)n_in; (void)out_size; (void)ws_size;
    const void* nf     = d_in[0];
    const int*  adj    = (const int*)d_in[2];
    const void* scaf   = d_in[3];
    const void* W_node = d_in[4];
    const void* b_node = d_in[5];
    const void* gat_W  = d_in[6];
    const void* gat_a  = d_in[7];
    const void* W_sc   = d_in[8];
    const void* b_sc   = d_in[9];
    const void* gp_w1  = d_in[10];
    const void* gp_b1  = d_in[11];
    const void* gp_w2  = d_in[12];
    const void* gp_b2  = d_in[13];
    const void* out_w1 = d_in[14];
    const void* out_b1 = d_in[15];
    const void* out_w2 = d_in[16];
    const void* out_b2 = d_in[17];

    float* ws    = (float*)d_ws;
    float* x     = ws;                      // 1048576 f32
    float* h     = ws + 1048576;            // 1048576 f32
    float* s1    = ws + 2097152;            // 4096
    float* s2    = s1 + 4096;               // 4096
    float* gpart = s2 + 4096;               // 131072
    u16*   Wrep  = (u16*)(gpart + 131072);  // 8 x 196608 u16
    u16*   Wnrep = Wrep + 8 * 196608;       // 8 x 19968 u16

    k_rep<<<424, 256, 0, stream>>>(gat_W, W_node, Wrep, Wnrep);
    for (int l = 0; l < 3; ++l) {
        k_gat<<<512, 256, 0, stream>>>(x, gat_W, Wrep, gat_a, l,
                                       nf, W_node, Wnrep, b_node, (l == 0) ? 1 : 0,
                                       h, s1, s2);
        k_attn<<<512, 256, 0, stream>>>(h, s1, s2, adj, x, gpart, (l == 2) ? 1 : 0);
    }
    k_head<<<32, 256, 0, stream>>>(gpart, scaf, W_sc, b_sc, gp_w1, gp_b1, gp_w2, gp_b2,
                                   out_w1, out_b1, out_w2, out_b2, d_out, W_node);
}